// Round 1
// baseline (756.142 us; speedup 1.0000x reference)
//
#include <hip/hip_runtime.h>

// RWKV6 WKV chunked linear attention, fp32.
// Shapes: B=8 H=16 T=4096 K=V=64. BH=128.
// Decomposition: coarse chunks CT=128 (NC=32), micro chunks L=32 (NM=4).
// kA: per (bh, coarse n) -> wkv chunk contribution (KxV) + coarse decay Dc (K)
// kB: per (bh,k,v) scan over n -> states at coarse-chunk starts (in-place) + final state
// kC: per (bh, coarse n) -> outputs (intra triangular + inter vs state), micro-chunked

#define BHn 128
#define Tn  4096
#define Kn  64
#define Vn  64
#define CTn 128
#define NCn 32
#define Ln  32
#define NMn 4
#define LP  68   // padded row stride for [.][64] fp32 LDS tiles
#define AP  36   // padded stride for A matrix
#define LOGMIN (-5.2983174f)   // log(0.005)

#define OUT_ELEMS 33554432     // B*H*T*V
#define WKVC_ELEMS 16777216    // BH*NC*K*V

__device__ __forceinline__ float4 ld4(const float* p) { return *(const float4*)p; }
__device__ __forceinline__ void st4(float* p, float4 v) { *(float4*)p = v; }

// ---------------- kernel A: coarse-chunk wkv + decay ----------------
__global__ __launch_bounds__(256)
void wkv_kA(const float* __restrict__ kg, const float* __restrict__ vg,
            const float* __restrict__ wg, float* __restrict__ wkvc,
            float* __restrict__ Dc)
{
    const int tid = threadIdx.x;
    const int n  = blockIdx.x & (NCn - 1);
    const int bh = blockIdx.x >> 5;
    __shared__ __align__(16) float wc[Ln][LP];
    __shared__ __align__(16) float kt[Ln][LP];
    __shared__ __align__(16) float vt[Ln][LP];
    __shared__ float dmv[Kn];

    const size_t base0 = (size_t)bh * Tn * Kn + (size_t)n * CTn * Kn;
    const int k0 = (tid >> 4) << 2;   // 0..60
    const int v0 = (tid & 15) << 2;   // 0..60

    // per-thread 4x4 state tile of the coarse wkv accumulator
    float4 W0 = {0,0,0,0}, W1 = W0, W2 = W0, W3 = W0;
    float dprod = 1.0f;

    for (int m = 0; m < NMn; ++m) {
        const size_t tb = base0 + (size_t)m * Ln * Kn;
#pragma unroll
        for (int j = 0; j < 2; ++j) {
            int i4 = tid + j * 256;
            int t = i4 >> 4, c = (i4 & 15) << 2;
            float4 a = ld4(wg + tb + (size_t)i4 * 4);
            a.x = fmaxf(a.x, LOGMIN); a.y = fmaxf(a.y, LOGMIN);
            a.z = fmaxf(a.z, LOGMIN); a.w = fmaxf(a.w, LOGMIN);
            st4(&wc[t][c], a);
            st4(&kt[t][c], ld4(kg + tb + (size_t)i4 * 4));
            st4(&vt[t][c], ld4(vg + tb + (size_t)i4 * 4));
        }
        __syncthreads();
        // suffix scan over t (descending): kt[t] *= exp(sum_{j>t} wlog[j])
        if (tid < Kn) {
            float suf = 0.f;
#pragma unroll
            for (int t8 = Ln - 8; t8 >= 0; t8 -= 8) {
                float x[8], y[8];
#pragma unroll
                for (int i = 0; i < 8; ++i) { x[i] = wc[t8 + i][tid]; y[i] = kt[t8 + i][tid]; }
#pragma unroll
                for (int i = 7; i >= 0; --i) { kt[t8 + i][tid] = y[i] * __expf(suf); suf += x[i]; }
            }
            float dm = __expf(suf);
            dmv[tid] = dm;
            dprod *= dm;
        }
        __syncthreads();
        // accumulate wkv_m = sum_t (k*w_inter)[t] outer v[t]; fold decay into running W
        float4 a0 = {0,0,0,0}, a1 = a0, a2 = a0, a3 = a0;
#pragma unroll 8
        for (int t = 0; t < Ln; ++t) {
            float4 kv = ld4(&kt[t][k0]);
            float4 vv = ld4(&vt[t][v0]);
            a0.x += kv.x * vv.x; a0.y += kv.x * vv.y; a0.z += kv.x * vv.z; a0.w += kv.x * vv.w;
            a1.x += kv.y * vv.x; a1.y += kv.y * vv.y; a1.z += kv.y * vv.z; a1.w += kv.y * vv.w;
            a2.x += kv.z * vv.x; a2.y += kv.z * vv.y; a2.z += kv.z * vv.z; a2.w += kv.z * vv.w;
            a3.x += kv.w * vv.x; a3.y += kv.w * vv.y; a3.z += kv.w * vv.z; a3.w += kv.w * vv.w;
        }
        float d0 = dmv[k0], d1 = dmv[k0 + 1], d2 = dmv[k0 + 2], d3 = dmv[k0 + 3];
        W0.x = W0.x * d0 + a0.x; W0.y = W0.y * d0 + a0.y; W0.z = W0.z * d0 + a0.z; W0.w = W0.w * d0 + a0.w;
        W1.x = W1.x * d1 + a1.x; W1.y = W1.y * d1 + a1.y; W1.z = W1.z * d1 + a1.z; W1.w = W1.w * d1 + a1.w;
        W2.x = W2.x * d2 + a2.x; W2.y = W2.y * d2 + a2.y; W2.z = W2.z * d2 + a2.z; W2.w = W2.w * d2 + a2.w;
        W3.x = W3.x * d3 + a3.x; W3.y = W3.y * d3 + a3.y; W3.z = W3.z * d3 + a3.z; W3.w = W3.w * d3 + a3.w;
        __syncthreads();   // before next micro overwrites tiles
    }
    float* wout = wkvc + ((size_t)(bh * NCn + n) << 12);
    st4(wout + (size_t)(k0 + 0) * Vn + v0, W0);
    st4(wout + (size_t)(k0 + 1) * Vn + v0, W1);
    st4(wout + (size_t)(k0 + 2) * Vn + v0, W2);
    st4(wout + (size_t)(k0 + 3) * Vn + v0, W3);
    if (tid < Kn) Dc[(bh * NCn + n) * Kn + tid] = dprod;
}

// ---------------- kernel B: scan over coarse chunks (in-place) ----------------
__global__ __launch_bounds__(256)
void wkv_kB(float* __restrict__ wkvc, const float* __restrict__ Dc,
            const float* __restrict__ s0g, float* __restrict__ fin)
{
    const int g = blockIdx.x * 256 + threadIdx.x;   // [0, BH*K*V)
    const int bh = g >> 12;
    const int rem = g & 4095;
    const int kq = rem >> 6;
    float S = s0g[g];
#pragma unroll 4
    for (int n2 = 0; n2 < NCn; ++n2) {
        size_t idx = ((size_t)(bh * NCn + n2) << 12) + rem;
        float tmp = wkvc[idx];
        wkvc[idx] = S;                              // state at start of chunk n2
        S = Dc[(bh * NCn + n2) * Kn + kq] * S + tmp;
    }
    fin[g] = S;
}

// ---------------- kernel C: outputs ----------------
__global__ __launch_bounds__(256)
void wkv_kC(const float* __restrict__ rg, const float* __restrict__ kg,
            const float* __restrict__ vg, const float* __restrict__ wg,
            const float* __restrict__ ug, const float* __restrict__ states,
            float* __restrict__ outg)
{
    const int tid = threadIdx.x;
    const int n  = blockIdx.x & (NCn - 1);
    const int bh = blockIdx.x >> 5;
    const int h  = bh & 15;

    __shared__ __align__(16) float wc[Ln][LP];
    __shared__ __align__(16) float rs[Ln][LP];
    __shared__ __align__(16) float ks[Ln][LP];
    __shared__ __align__(16) float vs[Ln][LP];
    __shared__ __align__(16) float Sl[Kn][LP];
    __shared__ float As[Ln][AP];
    __shared__ float offv[Kn], ev[Kn], gv[Kn], dmv[Kn];
    __shared__ __align__(16) float uv[Kn];
    __shared__ float diag4[Ln][4];

    {   // load state at this coarse chunk's start, and u
        const float* sp = states + ((size_t)(bh * NCn + n) << 12);
#pragma unroll
        for (int j = 0; j < 4; ++j) {
            int i4 = tid + j * 256;
            int kq = i4 >> 4, c = (i4 & 15) << 2;
            st4(&Sl[kq][c], ld4(sp + (size_t)i4 * 4));
        }
        if (tid < Kn) uv[tid] = ug[h * Kn + tid];
    }
    const size_t base0 = (size_t)bh * Tn * Kn + (size_t)n * CTn * Kn;
    __syncthreads();

    for (int m = 0; m < NMn; ++m) {
        const size_t tb = base0 + (size_t)m * Ln * Kn;
#pragma unroll
        for (int j = 0; j < 2; ++j) {
            int i4 = tid + j * 256;
            int t = i4 >> 4, c = (i4 & 15) << 2;
            float4 a = ld4(wg + tb + (size_t)i4 * 4);
            a.x = fmaxf(a.x, LOGMIN); a.y = fmaxf(a.y, LOGMIN);
            a.z = fmaxf(a.z, LOGMIN); a.w = fmaxf(a.w, LOGMIN);
            st4(&wc[t][c], a);
            st4(&rs[t][c], ld4(rg + tb + (size_t)i4 * 4));
            st4(&ks[t][c], ld4(kg + tb + (size_t)i4 * 4));
            st4(&vs[t][c], ld4(vg + tb + (size_t)i4 * 4));
        }
        __syncthreads();

        // wave0: inclusive cumsum of wlog over t (in place) + per-k constants
        // waves1-2: diag partials sum_k r*u*k (raw r,k)
        if (tid < Kn) {
            float acc = 0.f;
#pragma unroll
            for (int t8 = 0; t8 < Ln; t8 += 8) {
                float x[8];
#pragma unroll
                for (int i = 0; i < 8; ++i) x[i] = wc[t8 + i][tid];
#pragma unroll
                for (int i = 0; i < 8; ++i) { acc += x[i]; wc[t8 + i][tid] = acc; }
            }
            float off = wc[15][tid];           // = shifted[16], micro-center
            float wsv = wc[31][tid];           // total micro log-decay
            offv[tid] = off;
            float e = __expf(off), g2 = __expf(wsv - off);
            ev[tid] = e; gv[tid] = g2; dmv[tid] = e * g2;
        } else if (tid < 192) {
            int loc = tid - 64;
            int t = loc >> 2, p = loc & 3, c0 = p << 4;
            float d = 0.f;
#pragma unroll
            for (int c = 0; c < 16; c += 4) {
                float4 rv = ld4(&rs[t][c0 + c]);
                float4 kv = ld4(&ks[t][c0 + c]);
                float4 uu = ld4(&uv[c0 + c]);
                d += rv.x * kv.x * uu.x + rv.y * kv.y * uu.y + rv.z * kv.z * uu.z + rv.w * kv.w * uu.w;
            }
            diag4[t][p] = d;
        }
        __syncthreads();

        // scale: rs *= exp(shifted - off), ks *= exp(off - cumsum)
#pragma unroll
        for (int j = 0; j < 8; ++j) {
            int idx = tid + j * 256;
            int t = idx >> 6, c = idx & 63;
            float Wc = wc[t][c];
            float sh = t ? wc[t - 1][c] : 0.f;
            float off = offv[c];
            rs[t][c] *= __expf(sh - off);
            ks[t][c] *= __expf(off - Wc);
        }
        __syncthreads();

        // A GEMM (32x32 over K=64), thread -> (tp, tp+16) x (sq, sq+16)
        {
            const int tp = tid >> 4, sq = tid & 15;
            float a00 = 0.f, a10 = 0.f, a11 = 0.f;
#pragma unroll 4
            for (int c = 0; c < Kn; c += 4) {
                float4 r0 = ld4(&rs[tp][c]);
                float4 r1 = ld4(&rs[tp + 16][c]);
                float4 b0 = ld4(&ks[sq][c]);
                float4 b1 = ld4(&ks[sq + 16][c]);
                a00 += r0.x * b0.x + r0.y * b0.y + r0.z * b0.z + r0.w * b0.w;
                a10 += r1.x * b0.x + r1.y * b0.y + r1.z * b0.z + r1.w * b0.w;
                a11 += r1.x * b1.x + r1.y * b1.y + r1.z * b1.z + r1.w * b1.w;
            }
            float dg0 = diag4[tp][0] + diag4[tp][1] + diag4[tp][2] + diag4[tp][3];
            float dg1 = diag4[tp + 16][0] + diag4[tp + 16][1] + diag4[tp + 16][2] + diag4[tp + 16][3];
            As[tp][sq]           = (sq < tp) ? a00 : ((sq == tp) ? dg0 : 0.f);
            As[tp][sq + 16]      = 0.f;  // s=sq+16 >= 16 > tp always (upper triangle)
            As[tp + 16][sq]      = a10;  // sq < tp+16 always (strictly lower)
            As[tp + 16][sq + 16] = (sq < tp) ? a11 : ((sq == tp) ? dg1 : 0.f);
        }
        __syncthreads();

        // in-place: rs -> r*w_intra, ks -> k*w_inter
#pragma unroll
        for (int j = 0; j < 8; ++j) {
            int idx = tid + j * 256;
            int t = idx >> 6, c = idx & 63;
            rs[t][c] *= ev[c];
            ks[t][c] *= gv[c];
        }
        __syncthreads();

        // out = A @ v  +  (r*w_intra) @ Sl ; thread -> rows {tp, tp+16}, cols v0..v0+3
        {
            const int tp = tid >> 4, v0 = (tid & 15) << 2;
            float4 o0 = {0,0,0,0}, o1 = {0,0,0,0};
#pragma unroll 4
            for (int s = 0; s < Ln; ++s) {
                float4 vv = ld4(&vs[s][v0]);
                float x0 = As[tp][s], x1 = As[tp + 16][s];
                o0.x += x0 * vv.x; o0.y += x0 * vv.y; o0.z += x0 * vv.z; o0.w += x0 * vv.w;
                o1.x += x1 * vv.x; o1.y += x1 * vv.y; o1.z += x1 * vv.z; o1.w += x1 * vv.w;
            }
#pragma unroll 4
            for (int c = 0; c < Kn; ++c) {
                float4 sv = ld4(&Sl[c][v0]);
                float x0 = rs[tp][c], x1 = rs[tp + 16][c];
                o0.x += x0 * sv.x; o0.y += x0 * sv.y; o0.z += x0 * sv.z; o0.w += x0 * sv.w;
                o1.x += x1 * sv.x; o1.y += x1 * sv.y; o1.z += x1 * sv.z; o1.w += x1 * sv.w;
            }
            st4(outg + tb + (size_t)tp * Vn + v0, o0);
            st4(outg + tb + (size_t)(tp + 16) * Vn + v0, o1);
        }
        __syncthreads();

        // state update: Sl = dm * Sl + (k*w_inter)^T @ v
        {
            const int k0 = (tid >> 4) << 2, v0 = (tid & 15) << 2;
            float4 a0 = {0,0,0,0}, a1 = a0, a2 = a0, a3 = a0;
#pragma unroll 8
            for (int t = 0; t < Ln; ++t) {
                float4 kv = ld4(&ks[t][k0]);
                float4 vv = ld4(&vs[t][v0]);
                a0.x += kv.x * vv.x; a0.y += kv.x * vv.y; a0.z += kv.x * vv.z; a0.w += kv.x * vv.w;
                a1.x += kv.y * vv.x; a1.y += kv.y * vv.y; a1.z += kv.y * vv.z; a1.w += kv.y * vv.w;
                a2.x += kv.z * vv.x; a2.y += kv.z * vv.y; a2.z += kv.z * vv.z; a2.w += kv.z * vv.w;
                a3.x += kv.w * vv.x; a3.y += kv.w * vv.y; a3.z += kv.w * vv.z; a3.w += kv.w * vv.w;
            }
            float d0 = dmv[k0], d1 = dmv[k0 + 1], d2 = dmv[k0 + 2], d3 = dmv[k0 + 3];
            float4 s0v = ld4(&Sl[k0][v0]);
            s0v.x = s0v.x * d0 + a0.x; s0v.y = s0v.y * d0 + a0.y; s0v.z = s0v.z * d0 + a0.z; s0v.w = s0v.w * d0 + a0.w;
            st4(&Sl[k0][v0], s0v);
            float4 s1v = ld4(&Sl[k0 + 1][v0]);
            s1v.x = s1v.x * d1 + a1.x; s1v.y = s1v.y * d1 + a1.y; s1v.z = s1v.z * d1 + a1.z; s1v.w = s1v.w * d1 + a1.w;
            st4(&Sl[k0 + 1][v0], s1v);
            float4 s2v = ld4(&Sl[k0 + 2][v0]);
            s2v.x = s2v.x * d2 + a2.x; s2v.y = s2v.y * d2 + a2.y; s2v.z = s2v.z * d2 + a2.z; s2v.w = s2v.w * d2 + a2.w;
            st4(&Sl[k0 + 2][v0], s2v);
            float4 s3v = ld4(&Sl[k0 + 3][v0]);
            s3v.x = s3v.x * d3 + a3.x; s3v.y = s3v.y * d3 + a3.y; s3v.z = s3v.z * d3 + a3.z; s3v.w = s3v.w * d3 + a3.w;
            st4(&Sl[k0 + 3][v0], s3v);
        }
        __syncthreads();
    }
}

extern "C" void kernel_launch(void* const* d_in, const int* in_sizes, int n_in,
                              void* d_out, int out_size, void* d_ws, size_t ws_size,
                              hipStream_t stream) {
    const float* r  = (const float*)d_in[0];
    const float* k  = (const float*)d_in[1];
    const float* v  = (const float*)d_in[2];
    const float* w  = (const float*)d_in[3];
    const float* u  = (const float*)d_in[4];
    const float* s0 = (const float*)d_in[5];
    float* out = (float*)d_out;
    float* state_out = out + (size_t)OUT_ELEMS;
    float* wkvc = (float*)d_ws;                       // BH*NC*K*V fp32
    float* Dc   = wkvc + (size_t)WKVC_ELEMS;          // BH*NC*K fp32

    hipLaunchKernelGGL(wkv_kA, dim3(BHn * NCn), dim3(256), 0, stream, k, v, w, wkvc, Dc);
    hipLaunchKernelGGL(wkv_kB, dim3((BHn * Kn * Vn) / 256), dim3(256), 0, stream, wkvc, Dc, s0, state_out);
    hipLaunchKernelGGL(wkv_kC, dim3(BHn * NCn), dim3(256), 0, stream, r, k, v, w, u, wkvc, out);
}

// Round 2
// 603.860 us; speedup vs baseline: 1.2522x; 1.2522x over previous
//
#include <hip/hip_runtime.h>

// RWKV6 WKV chunked linear attention, bf16-MFMA version.
// Shapes: B=8 H=16 T=4096 K=V=64. BH=128.
// coarse chunks CT=128 (NC=32), micro chunks L=32 (NM=4), center at t=16.
// kA: per (bh,n) -> coarse wkv chunk W[v][k] + coarse decay Dc[k]   (MFMA state update)
// kB: per (bh,v,k) scan over n -> chunk-start states (in-place) + final state
// kC: per (bh,n) -> outputs via MFMA: A=Rp*Kp^T (masked+diag), out=A@V + Rp@(S*ev),
//     state acc regs updated via VT*KwT MFMA.

typedef __bf16 bf16_t;
typedef bf16_t bf16x8 __attribute__((ext_vector_type(8)));
typedef float f32x4 __attribute__((ext_vector_type(4)));

#define BHn 128
#define Tn  4096
#define Kn  64
#define CTn 128
#define NCn 32
#define Ln  32
#define NMn 4
#define WCS 68        // fp32 cumsum tile stride
#define RPS 72        // bf16 row-major tile stride (144B)
#define STS 72        // STb stride
#define ASS 40        // As stride (80B)
#define LOGMIN (-5.2983174f)
#define OUT_ELEMS 33554432
#define WKVC_ELEMS 16777216

__device__ __forceinline__ float4 ld4(const float* p){ return *(const float4*)p; }
__device__ __forceinline__ void st4(float* p, float4 v){ *(float4*)p = v; }

__device__ __forceinline__ f32x4 MFMA(bf16x8 a, bf16x8 b, f32x4 c){
    return __builtin_amdgcn_mfma_f32_16x16x32_bf16(a, b, c, 0, 0, 0);
}

// swizzled element offset in a [64-row][64-elem-stride(128B)] bf16 tile, data cols 0..31
__device__ __forceinline__ int swz(int row, int col){
    int b = (col << 1) ^ ((row & 7) << 4);
    return row * 64 + (b >> 1);
}
__device__ __forceinline__ int swzc(int row, int chunk){  // chunk = 16B block idx (0..3)
    int b = (chunk << 4) ^ ((row & 7) << 4);
    return row * 64 + (b >> 1);
}

// ---------------- kernel A: coarse-chunk wkv (MFMA) ----------------
__global__ __launch_bounds__(256)
void wkv_kA(const float* __restrict__ kg, const float* __restrict__ vg,
            const float* __restrict__ wg, float* __restrict__ wkvc,
            float* __restrict__ Dc)
{
    const int tid = threadIdx.x;
    const int lane = tid & 63, wv = tid >> 6;
    const int l16 = lane & 15, l4 = lane >> 4;
    const int n = blockIdx.x & 31, bh = blockIdx.x >> 5;

    __shared__ __align__(16) float wc[Ln * WCS];
    __shared__ __align__(16) float part[4][64];
    __shared__ __align__(16) float wsv[64], dmv[64];
    __shared__ __align__(16) bf16_t KwT[64 * 64];
    __shared__ __align__(16) bf16_t VT[64 * 64];

    const size_t base0 = (size_t)bh * Tn * Kn + (size_t)n * CTn * Kn;
    const int tA = tid >> 3, c0 = (tid & 7) * 8;
    const int vgrp4 = (tid & 15) * 4, trow2 = tid >> 4;

    f32x4 acc0 = {0,0,0,0}, acc1 = acc0, acc2 = acc0, acc3 = acc0;
    float dprod = 1.0f;

    for (int m = 0; m < NMn; ++m) {
        const size_t tb = base0 + (size_t)m * Ln * Kn;
        // P1: loads
        float4 k0v = ld4(kg + tb + (size_t)tA * 64 + c0);
        float4 k1v = ld4(kg + tb + (size_t)tA * 64 + c0 + 4);
        float4 w0 = ld4(wg + tb + (size_t)tA * 64 + c0);
        float4 w1 = ld4(wg + tb + (size_t)tA * 64 + c0 + 4);
        w0.x = fmaxf(w0.x, LOGMIN); w0.y = fmaxf(w0.y, LOGMIN);
        w0.z = fmaxf(w0.z, LOGMIN); w0.w = fmaxf(w0.w, LOGMIN);
        w1.x = fmaxf(w1.x, LOGMIN); w1.y = fmaxf(w1.y, LOGMIN);
        w1.z = fmaxf(w1.z, LOGMIN); w1.w = fmaxf(w1.w, LOGMIN);
        st4(&wc[tA * WCS + c0], w0);
        st4(&wc[tA * WCS + c0 + 4], w1);
        float4 va = ld4(vg + tb + (size_t)trow2 * 64 + vgrp4);
        float4 vb = ld4(vg + tb + (size_t)(trow2 + 16) * 64 + vgrp4);
        VT[swz(vgrp4 + 0, trow2)] = (bf16_t)va.x;
        VT[swz(vgrp4 + 1, trow2)] = (bf16_t)va.y;
        VT[swz(vgrp4 + 2, trow2)] = (bf16_t)va.z;
        VT[swz(vgrp4 + 3, trow2)] = (bf16_t)va.w;
        VT[swz(vgrp4 + 0, trow2 + 16)] = (bf16_t)vb.x;
        VT[swz(vgrp4 + 1, trow2 + 16)] = (bf16_t)vb.y;
        VT[swz(vgrp4 + 2, trow2 + 16)] = (bf16_t)vb.z;
        VT[swz(vgrp4 + 3, trow2 + 16)] = (bf16_t)vb.w;
        __syncthreads();                                   // B1
        // P2: cumsum partials
        float x[8];
        {
            int c = tid & 63, tg = tid >> 6;
            float s = 0.f;
#pragma unroll
            for (int i = 0; i < 8; ++i) { x[i] = wc[(8 * tg + i) * WCS + c]; s += x[i]; }
            part[tg][c] = s;
        }
        __syncthreads();                                   // B2
        // P2c: scan + writeback
        {
            int c = tid & 63, tg = tid >> 6;
            float pre = 0.f;
            if (tg > 0) pre += part[0][c];
            if (tg > 1) pre += part[1][c];
            if (tg > 2) pre += part[2][c];
            float a = pre;
#pragma unroll
            for (int i = 0; i < 8; ++i) { a += x[i]; wc[(8 * tg + i) * WCS + c] = a; }
            if (tg == 3) wsv[c] = a;
        }
        __syncthreads();                                   // B3
        // P3: KwT write + dm
        if (tid < 64) {
            float d = __expf(wsv[tid]);
            dmv[tid] = d;
            dprod *= d;
        }
        {
            float kk[8] = {k0v.x, k0v.y, k0v.z, k0v.w, k1v.x, k1v.y, k1v.z, k1v.w};
            float cum[8];
            *(float4*)&cum[0] = ld4(&wc[tA * WCS + c0]);
            *(float4*)&cum[4] = ld4(&wc[tA * WCS + c0 + 4]);
            float ws8[8];
            *(float4*)&ws8[0] = ld4(&wsv[c0]);
            *(float4*)&ws8[4] = ld4(&wsv[c0 + 4]);
#pragma unroll
            for (int i = 0; i < 8; ++i) {
                float kw = kk[i] * __expf(ws8[i] - cum[i]);
                KwT[swz(c0 + i, tA)] = (bf16_t)kw;
            }
        }
        __syncthreads();                                   // B4
        // P4: state MFMA
        {
            bf16x8 vtf = *(const bf16x8*)&VT[swzc(16 * wv + l16, l4)];
            bf16x8 kf0 = *(const bf16x8*)&KwT[swzc(l16, l4)];
            bf16x8 kf1 = *(const bf16x8*)&KwT[swzc(16 + l16, l4)];
            bf16x8 kf2 = *(const bf16x8*)&KwT[swzc(32 + l16, l4)];
            bf16x8 kf3 = *(const bf16x8*)&KwT[swzc(48 + l16, l4)];
            float dm0 = dmv[l16], dm1 = dmv[16 + l16], dm2 = dmv[32 + l16], dm3 = dmv[48 + l16];
#pragma unroll
            for (int q = 0; q < 4; ++q) { acc0[q] *= dm0; acc1[q] *= dm1; acc2[q] *= dm2; acc3[q] *= dm3; }
            acc0 = MFMA(vtf, kf0, acc0);
            acc1 = MFMA(vtf, kf1, acc1);
            acc2 = MFMA(vtf, kf2, acc2);
            acc3 = MFMA(vtf, kf3, acc3);
        }
        __syncthreads();                                   // B5 (protect wc/VT rewrite)
    }
    // write W[v][k] and Dc
    float* wout = wkvc + ((size_t)(bh * NCn + n) << 12);
    {
        int vrow = 16 * wv + 4 * l4;
#pragma unroll
        for (int q = 0; q < 4; ++q) {
            wout[(vrow + q) * 64 + l16]      = acc0[q];
            wout[(vrow + q) * 64 + 16 + l16] = acc1[q];
            wout[(vrow + q) * 64 + 32 + l16] = acc2[q];
            wout[(vrow + q) * 64 + 48 + l16] = acc3[q];
        }
    }
    if (tid < 64) Dc[(bh * NCn + n) * 64 + tid] = dprod;
}

// ---------------- kernel B: scan over coarse chunks (in-place) ----------------
__global__ __launch_bounds__(256)
void wkv_kB(float* __restrict__ wkvc, const float* __restrict__ Dc,
            const float* __restrict__ s0g, float* __restrict__ fin)
{
    const int g = blockIdx.x * 256 + threadIdx.x;   // [0, BH*4096)
    const int bh = g >> 12;
    const int rem = g & 4095;                        // rem = v*64 + k
    const int kq = rem & 63;
    const int vq = rem >> 6;
    float S = s0g[bh * 4096 + kq * 64 + vq];         // input state is [k][v]
#pragma unroll 4
    for (int n2 = 0; n2 < NCn; ++n2) {
        size_t idx = ((size_t)(bh * NCn + n2) << 12) + rem;
        float tmp = wkvc[idx];
        wkvc[idx] = S;                               // state at start of chunk n2, [v][k]
        S = Dc[(bh * NCn + n2) * 64 + kq] * S + tmp;
    }
    fin[bh * 4096 + kq * 64 + vq] = S;               // final state back to [k][v]
}

// ---------------- kernel C: outputs (MFMA) ----------------
__global__ __launch_bounds__(256)
void wkv_kC(const float* __restrict__ rg, const float* __restrict__ kg,
            const float* __restrict__ vg, const float* __restrict__ wg,
            const float* __restrict__ ug, const float* __restrict__ states,
            float* __restrict__ outg)
{
    const int tid = threadIdx.x;
    const int lane = tid & 63, wv = tid >> 6;
    const int l16 = lane & 15, l4 = lane >> 4;
    const int n = blockIdx.x & 31, bh = blockIdx.x >> 5, h = bh & 15;

    __shared__ __align__(16) float wc[Ln * WCS];
    __shared__ __align__(16) float part[4][64];
    __shared__ __align__(16) float offv[64], wsv[64], evv[64], gvv[64], dmv[64];
    __shared__ __align__(16) float u_s[64];
    __shared__ float diagp[32][8];
    __shared__ float diagv[32];
    __shared__ __align__(16) bf16_t Rp[Ln * RPS], Kp[Ln * RPS];
    __shared__ __align__(16) bf16_t KpT[64 * 64], VT[64 * 64];
    __shared__ __align__(16) bf16_t STb[64 * STS];
    __shared__ __align__(16) bf16_t As[Ln * ASS];

    if (tid < 64) u_s[tid] = ug[h * 64 + tid];

    // state in acc regs: wave wv owns v-rows [16wv, 16wv+16), cols k (4 tiles)
    const float* sp = states + ((size_t)(bh * NCn + n) << 12);
    f32x4 acc0, acc1, acc2, acc3;
    {
        int vrow = 16 * wv + 4 * l4;
#pragma unroll
        for (int q = 0; q < 4; ++q) {
            acc0[q] = sp[(vrow + q) * 64 + l16];
            acc1[q] = sp[(vrow + q) * 64 + 16 + l16];
            acc2[q] = sp[(vrow + q) * 64 + 32 + l16];
            acc3[q] = sp[(vrow + q) * 64 + 48 + l16];
        }
    }
    const size_t base0 = (size_t)bh * Tn * Kn + (size_t)n * CTn * Kn;
    const int tA = tid >> 3, c0 = (tid & 7) * 8;
    const int vgrp4 = (tid & 15) * 4, trow2 = tid >> 4;

    for (int m = 0; m < NMn; ++m) {
        const size_t tb = base0 + (size_t)m * Ln * Kn;
        // ---- P1: loads ----
        float4 r0 = ld4(rg + tb + (size_t)tA * 64 + c0);
        float4 r1 = ld4(rg + tb + (size_t)tA * 64 + c0 + 4);
        float4 k0v = ld4(kg + tb + (size_t)tA * 64 + c0);
        float4 k1v = ld4(kg + tb + (size_t)tA * 64 + c0 + 4);
        float4 w0 = ld4(wg + tb + (size_t)tA * 64 + c0);
        float4 w1 = ld4(wg + tb + (size_t)tA * 64 + c0 + 4);
        w0.x = fmaxf(w0.x, LOGMIN); w0.y = fmaxf(w0.y, LOGMIN);
        w0.z = fmaxf(w0.z, LOGMIN); w0.w = fmaxf(w0.w, LOGMIN);
        w1.x = fmaxf(w1.x, LOGMIN); w1.y = fmaxf(w1.y, LOGMIN);
        w1.z = fmaxf(w1.z, LOGMIN); w1.w = fmaxf(w1.w, LOGMIN);
        st4(&wc[tA * WCS + c0], w0);
        st4(&wc[tA * WCS + c0 + 4], w1);
        float4 va = ld4(vg + tb + (size_t)trow2 * 64 + vgrp4);
        float4 vb = ld4(vg + tb + (size_t)(trow2 + 16) * 64 + vgrp4);
        VT[swz(vgrp4 + 0, trow2)] = (bf16_t)va.x;
        VT[swz(vgrp4 + 1, trow2)] = (bf16_t)va.y;
        VT[swz(vgrp4 + 2, trow2)] = (bf16_t)va.z;
        VT[swz(vgrp4 + 3, trow2)] = (bf16_t)va.w;
        VT[swz(vgrp4 + 0, trow2 + 16)] = (bf16_t)vb.x;
        VT[swz(vgrp4 + 1, trow2 + 16)] = (bf16_t)vb.y;
        VT[swz(vgrp4 + 2, trow2 + 16)] = (bf16_t)vb.z;
        VT[swz(vgrp4 + 3, trow2 + 16)] = (bf16_t)vb.w;
        __syncthreads();                               // B1
        // ---- P2: cumsum partials + diag partials ----
        float x[8];
        {
            int c = tid & 63, tg = tid >> 6;
            float s = 0.f;
#pragma unroll
            for (int i = 0; i < 8; ++i) { x[i] = wc[(8 * tg + i) * WCS + c]; s += x[i]; }
            part[tg][c] = s;
        }
        {
            float d = r0.x * u_s[c0 + 0] * k0v.x + r0.y * u_s[c0 + 1] * k0v.y
                    + r0.z * u_s[c0 + 2] * k0v.z + r0.w * u_s[c0 + 3] * k0v.w
                    + r1.x * u_s[c0 + 4] * k1v.x + r1.y * u_s[c0 + 5] * k1v.y
                    + r1.z * u_s[c0 + 6] * k1v.z + r1.w * u_s[c0 + 7] * k1v.w;
            diagp[tA][tid & 7] = d;
        }
        __syncthreads();                               // B2
        // ---- P2c: scan + writeback ----
        {
            int c = tid & 63, tg = tid >> 6;
            float pre = 0.f;
            if (tg > 0) pre += part[0][c];
            if (tg > 1) pre += part[1][c];
            if (tg > 2) pre += part[2][c];
            float a = pre;
#pragma unroll
            for (int i = 0; i < 8; ++i) { a += x[i]; wc[(8 * tg + i) * WCS + c] = a; }
            if (tg == 1) offv[c] = a;                  // cum[15]
            if (tg == 3) wsv[c] = a;                   // cum[31]
        }
        __syncthreads();                               // B3
        // ---- P2d: per-k constants + diag sums ----
        if (tid < 64) {
            float off = offv[tid], ws = wsv[tid];
            evv[tid] = __expf(off);
            gvv[tid] = __expf(ws - off);
            dmv[tid] = __expf(ws);
        } else if (tid < 96) {
            int t = tid - 64; float s = 0.f;
#pragma unroll
            for (int g2 = 0; g2 < 8; ++g2) s += diagp[t][g2];
            diagv[t] = s;
        }
        __syncthreads();                               // B4
        // ---- P3: scale + bf16 operand tiles ----
        {
            float rr[8] = {r0.x, r0.y, r0.z, r0.w, r1.x, r1.y, r1.z, r1.w};
            float kk[8] = {k0v.x, k0v.y, k0v.z, k0v.w, k1v.x, k1v.y, k1v.z, k1v.w};
            float cum[8], sh[8], of[8], gl[8];
            *(float4*)&cum[0] = ld4(&wc[tA * WCS + c0]);
            *(float4*)&cum[4] = ld4(&wc[tA * WCS + c0 + 4]);
            if (tA > 0) {
                *(float4*)&sh[0] = ld4(&wc[(tA - 1) * WCS + c0]);
                *(float4*)&sh[4] = ld4(&wc[(tA - 1) * WCS + c0 + 4]);
            } else {
#pragma unroll
                for (int i = 0; i < 8; ++i) sh[i] = 0.f;
            }
            *(float4*)&of[0] = ld4(&offv[c0]);
            *(float4*)&of[4] = ld4(&offv[c0 + 4]);
            *(float4*)&gl[0] = ld4(&gvv[c0]);
            *(float4*)&gl[4] = ld4(&gvv[c0 + 4]);
            bf16x8 rpv, kpv;
#pragma unroll
            for (int i = 0; i < 8; ++i) {
                float rp = rr[i] * __expf(sh[i] - of[i]);
                float kp = kk[i] * __expf(of[i] - cum[i]);
                rpv[i] = (bf16_t)rp;
                kpv[i] = (bf16_t)kp;
                KpT[swz(c0 + i, tA)] = (bf16_t)(kp * gl[i]);   // Kw^T (gv folded)
            }
            *(bf16x8*)&Rp[tA * RPS + c0] = rpv;
            *(bf16x8*)&Kp[tA * RPS + c0] = kpv;
        }
        __syncthreads();                               // B5
        // ---- P4: STb (ev folded) + A-GEMM ----
        {
            int vrow = 16 * wv + 4 * l4;
            float e0 = evv[l16], e1 = evv[16 + l16], e2 = evv[32 + l16], e3 = evv[48 + l16];
#pragma unroll
            for (int q = 0; q < 4; ++q) {
                STb[(vrow + q) * STS + l16]      = (bf16_t)(acc0[q] * e0);
                STb[(vrow + q) * STS + 16 + l16] = (bf16_t)(acc1[q] * e1);
                STb[(vrow + q) * STS + 32 + l16] = (bf16_t)(acc2[q] * e2);
                STb[(vrow + q) * STS + 48 + l16] = (bf16_t)(acc3[q] * e3);
            }
            int tt = wv >> 1, ts = wv & 1;
            bf16x8 a0 = *(const bf16x8*)&Rp[(16 * tt + l16) * RPS + l4 * 8];
            bf16x8 a1 = *(const bf16x8*)&Rp[(16 * tt + l16) * RPS + 32 + l4 * 8];
            bf16x8 b0 = *(const bf16x8*)&Kp[(16 * ts + l16) * RPS + l4 * 8];
            bf16x8 b1 = *(const bf16x8*)&Kp[(16 * ts + l16) * RPS + 32 + l4 * 8];
            f32x4 d = {0, 0, 0, 0};
            d = MFMA(a0, b0, d);
            d = MFMA(a1, b1, d);
            int trow = 16 * tt + 4 * l4, s = 16 * ts + l16;
#pragma unroll
            for (int q = 0; q < 4; ++q) {
                int t = trow + q;
                float val = (s < t) ? d[q] : ((s == t) ? diagv[t] : 0.f);
                As[t * ASS + s] = (bf16_t)val;
            }
        }
        __syncthreads();                               // B6
        // ---- P6: out MFMAs + store; P7: state update (read-only LDS, no barrier) ----
        {
            int vt = wv;
            bf16x8 sb0 = *(const bf16x8*)&STb[(16 * vt + l16) * STS + l4 * 8];
            bf16x8 sb1 = *(const bf16x8*)&STb[(16 * vt + l16) * STS + 32 + l4 * 8];
            bf16x8 vtf = *(const bf16x8*)&VT[swzc(16 * vt + l16, l4)];
#pragma unroll
            for (int tt = 0; tt < 2; ++tt) {
                bf16x8 ra0 = *(const bf16x8*)&Rp[(16 * tt + l16) * RPS + l4 * 8];
                bf16x8 ra1 = *(const bf16x8*)&Rp[(16 * tt + l16) * RPS + 32 + l4 * 8];
                bf16x8 af  = *(const bf16x8*)&As[(16 * tt + l16) * ASS + l4 * 8];
                f32x4 o = {0, 0, 0, 0};
                o = MFMA(ra0, sb0, o);
                o = MFMA(ra1, sb1, o);
                o = MFMA(af, vtf, o);
                int trow = 16 * tt + 4 * l4;
#pragma unroll
                for (int q = 0; q < 4; ++q)
                    outg[tb + (size_t)(trow + q) * 64 + 16 * vt + l16] = o[q];
            }
            // P7: state update
            bf16x8 kf0 = *(const bf16x8*)&KpT[swzc(l16, l4)];
            bf16x8 kf1 = *(const bf16x8*)&KpT[swzc(16 + l16, l4)];
            bf16x8 kf2 = *(const bf16x8*)&KpT[swzc(32 + l16, l4)];
            bf16x8 kf3 = *(const bf16x8*)&KpT[swzc(48 + l16, l4)];
            float dm0 = dmv[l16], dm1 = dmv[16 + l16], dm2 = dmv[32 + l16], dm3 = dmv[48 + l16];
#pragma unroll
            for (int q = 0; q < 4; ++q) { acc0[q] *= dm0; acc1[q] *= dm1; acc2[q] *= dm2; acc3[q] *= dm3; }
            acc0 = MFMA(vtf, kf0, acc0);
            acc1 = MFMA(vtf, kf1, acc1);
            acc2 = MFMA(vtf, kf2, acc2);
            acc3 = MFMA(vtf, kf3, acc3);
        }
        __syncthreads();                               // B7
    }
}

extern "C" void kernel_launch(void* const* d_in, const int* in_sizes, int n_in,
                              void* d_out, int out_size, void* d_ws, size_t ws_size,
                              hipStream_t stream) {
    const float* r  = (const float*)d_in[0];
    const float* k  = (const float*)d_in[1];
    const float* v  = (const float*)d_in[2];
    const float* w  = (const float*)d_in[3];
    const float* u  = (const float*)d_in[4];
    const float* s0 = (const float*)d_in[5];
    float* out = (float*)d_out;
    float* state_out = out + (size_t)OUT_ELEMS;
    float* wkvc = (float*)d_ws;                        // BH*NC*64*64 fp32, [v][k] per chunk
    float* Dc   = wkvc + (size_t)WKVC_ELEMS;           // BH*NC*64 fp32

    hipLaunchKernelGGL(wkv_kA, dim3(BHn * NCn), dim3(256), 0, stream, k, v, w, wkvc, Dc);
    hipLaunchKernelGGL(wkv_kB, dim3((BHn * 4096) / 256), dim3(256), 0, stream, wkvc, Dc, s0, state_out);
    hipLaunchKernelGGL(wkv_kC, dim3(BHn * NCn), dim3(256), 0, stream, r, k, v, w, u, wkvc, out);
}